// Round 7
// baseline (1166.019 us; speedup 1.0000x reference)
//
#include <hip/hip_runtime.h>
#include <hip/hip_bf16.h>

#define N_NODES 100000
#define N_EDGES 3200000
#define HID 16
#define MAXDEG 128   // combined degree: mean 64, sigma 8; max@100K nodes ~100
#define NXCD 8       // blockIdx%8 -> XCD group (dispatch heuristic)
#define SUBP 4       // sequential node-subranges per XCD group
#define NPARTS (NXCD * SUBP)              // 32
#define PART_NODES (N_NODES / NPARTS)     // 3125; window = 3125*128*4B = 1.6MB

static constexpr int BLK = 256;

typedef int v4i __attribute__((ext_vector_type(4)));  // native vec for NT load

__device__ __forceinline__ float frelu(float x) { return fmaxf(x, 0.f); }
__device__ __forceinline__ float bf2f(unsigned short u) {
  return __uint_as_float(((unsigned int)u) << 16);
}

// 16 bf16 (32 B) viewed as two float4 for vector load/store
union E16 {
  float4 f4[2];
  __hip_bfloat16 h[16];
};

// ---------------------------------------------------------------------------
// K0: norm = max |edges_init|
// ---------------------------------------------------------------------------
__global__ __launch_bounds__(256) void k_norm(const float* __restrict__ edges,
                                              unsigned int* __restrict__ normbits) {
  float m = 0.f;
  for (int i = blockIdx.x * blockDim.x + threadIdx.x; i < N_EDGES;
       i += gridDim.x * blockDim.x)
    m = fmaxf(m, fabsf(edges[i]));
#pragma unroll
  for (int off = 32; off > 0; off >>= 1)
    m = fmaxf(m, __shfl_down(m, off, 64));
  __shared__ float smax[BLK / 64];
  if ((threadIdx.x & 63) == 0) smax[threadIdx.x >> 6] = m;
  __syncthreads();
  if (threadIdx.x == 0) {
    float b = smax[0];
#pragma unroll
    for (int w = 1; w < BLK / 64; ++w) b = fmaxf(b, smax[w]);
    atomicMax(normbits, __float_as_uint(b));
  }
}

// ---------------------------------------------------------------------------
// K1: ELL build, v3 (compile-fixed). blockIdx%8 selects an XCD group (same
// 3520-block geometry as rounds 4/5). Each group serially handles SUBP=4
// node-subranges of 3125 nodes; dirty ELL window per sub-pass = 1.6 MB <<
// 4 MB L2, so a node's entry lines stay L2-resident for the whole sub-pass
// and write back once (R4/R5's 6.4 MB window exceeded L2 -> writeback per
// ~2.7 entries, WRITE_SIZE 266-308 MB). senders/receivers scanned as
// nontemporal ext-vector int4; the 4x re-read is served by L3 (25.6 MB).
// entry = (edge<<1)|side
// ---------------------------------------------------------------------------
__global__ __launch_bounds__(256) void k_build(const int* __restrict__ senders,
                                               const int* __restrict__ receivers,
                                               int* __restrict__ count,
                                               int* __restrict__ ell) {
  int xcd = blockIdx.x & (NXCD - 1);
  int q = blockIdx.x >> 3;
  int nblk = gridDim.x >> 3;
  const v4i* s4p = (const v4i*)senders;
  const v4i* r4p = (const v4i*)receivers;
  const int nvec = N_EDGES / 4;  // 800000 exactly
  for (int sub = 0; sub < SUBP; ++sub) {
    int part = xcd * SUBP + sub;
    int lo = part * PART_NODES, hi = lo + PART_NODES;
    for (int v = q * blockDim.x + threadIdx.x; v < nvec; v += nblk * blockDim.x) {
      v4i s4 = __builtin_nontemporal_load(s4p + v);
      v4i r4 = __builtin_nontemporal_load(r4p + v);
      int base = v * 4;
#pragma unroll
      for (int t = 0; t < 4; ++t) {
        int s = s4[t];
        if (s >= lo && s < hi) {
          int slot = atomicAdd(&count[s], 1);
          if (slot < MAXDEG) ell[(size_t)s * MAXDEG + slot] = ((base + t) << 1);
        }
        int r = r4[t];
        if (r >= lo && r < hi) {
          int slot = atomicAdd(&count[r], 1);
          if (slot < MAXDEG) ell[(size_t)r * MAXDEG + slot] = ((base + t) << 1) | 1;
        }
      }
    }
  }
}

// ---------------------------------------------------------------------------
// K2: edge encoder (1 -> HID -> HID), writes e (bf16)
// ---------------------------------------------------------------------------
__global__ __launch_bounds__(256) void k_encode(
    const float* __restrict__ edges, const float* __restrict__ w1,
    const float* __restrict__ b1, const float* __restrict__ w2,
    const float* __restrict__ b2, const unsigned int* __restrict__ normbits,
    __hip_bfloat16* __restrict__ e) {
  int i = blockIdx.x * blockDim.x + threadIdx.x;
  if (i >= N_EDGES) return;
  float norm = __uint_as_float(*normbits);
  float x = edges[i] / norm;
  float h[HID];
#pragma unroll
  for (int j = 0; j < HID; ++j) h[j] = frelu(fmaf(w1[j], x, b1[j]));
  E16 o;
#pragma unroll
  for (int j = 0; j < HID; ++j) {
    float acc = b2[j];
#pragma unroll
    for (int k = 0; k < HID; ++k) acc = fmaf(w2[j * HID + k], h[k], acc);
    o.h[j] = __float2bfloat16(acc);
  }
  float4* ep = (float4*)(e + (size_t)i * HID);
  ep[0] = o.f4[0];
  ep[1] = o.f4[1];
}

// ---------------------------------------------------------------------------
// K3: gather v2 — one 64-lane wave per node, 4 lanes per edge, 8 B loads.
// ~64 random 64B-lines in flight per wave; measured ~2 TB/s granule rate
// (chip random-access ceiling). Unchanged this round.
// ---------------------------------------------------------------------------
__global__ __launch_bounds__(256) void k_gather(
    const unsigned short* __restrict__ e, const int* __restrict__ count,
    const int* __restrict__ ell, float* __restrict__ agg) {
  int wave = (blockIdx.x * blockDim.x + threadIdx.x) >> 6;
  int lane = threadIdx.x & 63;
  if (wave >= N_NODES) return;
  int n = wave;
  int deg = count[n];
  if (deg > MAXDEG) deg = MAXDEG;
  const int* lst = ell + (size_t)n * MAXDEG;
  int sub = lane & 3;  // which 4-channel quarter this lane owns
  float as0 = 0.f, as1 = 0.f, as2 = 0.f, as3 = 0.f;
  float ar0 = 0.f, ar1 = 0.f, ar2 = 0.f, ar3 = 0.f;
  for (int k0 = 0; k0 < deg; k0 += 64) {
    int ent = lst[k0 + lane];  // always in-bounds (MAXDEG=128, k0<=64)
#pragma unroll
    for (int t = 0; t < 4; ++t) {
      int slot = k0 + t * 16 + (lane >> 2);
      int entry = __shfl(ent, t * 16 + (lane >> 2), 64);
      bool ok = slot < deg;
      int edge = ok ? (entry >> 1) : 0;  // clamp garbage slots to a safe addr
      ushort4 raw = *(const ushort4*)(e + (size_t)edge * HID + sub * 4);
      float v0 = bf2f(raw.x), v1 = bf2f(raw.y), v2 = bf2f(raw.z),
            v3 = bf2f(raw.w);
      bool recv = ok && (entry & 1);
      bool send = ok && !(entry & 1);
      as0 += send ? v0 : 0.f;  as1 += send ? v1 : 0.f;
      as2 += send ? v2 : 0.f;  as3 += send ? v3 : 0.f;
      ar0 += recv ? v0 : 0.f;  ar1 += recv ? v1 : 0.f;
      ar2 += recv ? v2 : 0.f;  ar3 += recv ? v3 : 0.f;
    }
  }
  // reduce the 16 stride-4 lane-groups down to lanes 0..3
#pragma unroll
  for (int off = 32; off >= 4; off >>= 1) {
    as0 += __shfl_down(as0, off, 64);  as1 += __shfl_down(as1, off, 64);
    as2 += __shfl_down(as2, off, 64);  as3 += __shfl_down(as3, off, 64);
    ar0 += __shfl_down(ar0, off, 64);  ar1 += __shfl_down(ar1, off, 64);
    ar2 += __shfl_down(ar2, off, 64);  ar3 += __shfl_down(ar3, off, 64);
  }
  if (lane < 4) {
    *(float4*)(agg + (size_t)n * 32 + lane * 4) = make_float4(as0, as1, as2, as3);
    *(float4*)(agg + (size_t)n * 32 + 16 + lane * 4) = make_float4(ar0, ar1, ar2, ar3);
  }
}

// ---------------------------------------------------------------------------
// K4: node MLP (1+2H -> HID -> 1). w1 is [16][33]
// ---------------------------------------------------------------------------
__global__ __launch_bounds__(256) void k_node(
    const float* __restrict__ nodes_in, const float* __restrict__ agg,
    const float* __restrict__ w1, const float* __restrict__ b1,
    const float* __restrict__ w2, const float* __restrict__ b2,
    float* __restrict__ nodes_out) {
  int n = blockIdx.x * blockDim.x + threadIdx.x;
  if (n >= N_NODES) return;
  float x0 = nodes_in[n];
  const float4* ap = (const float4*)(agg + (size_t)n * 32);
  float av[32];
#pragma unroll
  for (int q = 0; q < 8; ++q) {
    float4 v = ap[q];
    av[q * 4 + 0] = v.x;
    av[q * 4 + 1] = v.y;
    av[q * 4 + 2] = v.z;
    av[q * 4 + 3] = v.w;
  }
  float out = b2[0];
#pragma unroll
  for (int j = 0; j < HID; ++j) {
    float acc = fmaf(w1[j * 33], x0, b1[j]);
#pragma unroll
    for (int k = 0; k < 32; ++k) acc = fmaf(w1[j * 33 + 1 + k], av[k], acc);
    out = fmaf(w2[j], frelu(acc), out);
  }
  nodes_out[n] = out;
}

// ---------------------------------------------------------------------------
// K5: edge MLP (H+2 -> HID -> HID), in-place on e (bf16 storage, fp32 math)
// ---------------------------------------------------------------------------
__global__ __launch_bounds__(256) void k_edge(
    __hip_bfloat16* __restrict__ e, const int* __restrict__ senders,
    const int* __restrict__ receivers, const float* __restrict__ nodes,
    const float* __restrict__ w1, const float* __restrict__ b1,
    const float* __restrict__ w2, const float* __restrict__ b2) {
  int i = blockIdx.x * blockDim.x + threadIdx.x;
  if (i >= N_EDGES) return;
  int s = senders[i], r = receivers[i];
  float ns = nodes[s], nr = nodes[r];
  float4* ep = (float4*)(e + (size_t)i * HID);
  E16 in;
  in.f4[0] = ep[0];
  in.f4[1] = ep[1];
  float x[HID];
#pragma unroll
  for (int k = 0; k < HID; ++k) x[k] = __bfloat162float(in.h[k]);
  float h[HID];
#pragma unroll
  for (int j = 0; j < HID; ++j) {
    float acc = b1[j];
#pragma unroll
    for (int k = 0; k < HID; ++k) acc = fmaf(w1[j * 18 + k], x[k], acc);
    acc = fmaf(w1[j * 18 + 16], ns, acc);
    acc = fmaf(w1[j * 18 + 17], nr, acc);
    h[j] = frelu(acc);
  }
  E16 o;
#pragma unroll
  for (int j = 0; j < HID; ++j) {
    float acc = b2[j];
#pragma unroll
    for (int k = 0; k < HID; ++k) acc = fmaf(w2[j * HID + k], h[k], acc);
    o.h[j] = __float2bfloat16(acc);
  }
  ep[0] = o.f4[0];
  ep[1] = o.f4[1];
}

// ---------------------------------------------------------------------------
// K6: round-3 edge MLP + decoder + out = edges + alpha*e*norm
// ---------------------------------------------------------------------------
__global__ __launch_bounds__(256) void k_final(
    const __hip_bfloat16* __restrict__ e, const int* __restrict__ senders,
    const int* __restrict__ receivers, const float* __restrict__ nodes,
    const float* __restrict__ w1, const float* __restrict__ b1,
    const float* __restrict__ w2, const float* __restrict__ b2,
    const float* __restrict__ dw1, const float* __restrict__ db1,
    const float* __restrict__ dw2, const float* __restrict__ db2,
    const float* __restrict__ edges_init,
    const unsigned int* __restrict__ normbits, const float* __restrict__ alpha,
    float* __restrict__ out) {
  int i = blockIdx.x * blockDim.x + threadIdx.x;
  if (i >= N_EDGES) return;
  int s = senders[i], r = receivers[i];
  float ns = nodes[s], nr = nodes[r];
  const float4* ep = (const float4*)(e + (size_t)i * HID);
  E16 in;
  in.f4[0] = ep[0];
  in.f4[1] = ep[1];
  float x[HID];
#pragma unroll
  for (int k = 0; k < HID; ++k) x[k] = __bfloat162float(in.h[k]);
  float h[HID];
#pragma unroll
  for (int j = 0; j < HID; ++j) {
    float acc = b1[j];
#pragma unroll
    for (int k = 0; k < HID; ++k) acc = fmaf(w1[j * 18 + k], x[k], acc);
    acc = fmaf(w1[j * 18 + 16], ns, acc);
    acc = fmaf(w1[j * 18 + 17], nr, acc);
    h[j] = frelu(acc);
  }
  float e3[HID];
#pragma unroll
  for (int j = 0; j < HID; ++j) {
    float acc = b2[j];
#pragma unroll
    for (int k = 0; k < HID; ++k) acc = fmaf(w2[j * HID + k], h[k], acc);
    e3[j] = acc;
  }
  float d = db2[0];
#pragma unroll
  for (int j = 0; j < HID; ++j) {
    float acc = db1[j];
#pragma unroll
    for (int k = 0; k < HID; ++k) acc = fmaf(dw1[j * HID + k], e3[k], acc);
    d = fmaf(dw2[j], frelu(acc), d);
  }
  float norm = __uint_as_float(*normbits);
  out[i] = fmaf(alpha[0], d * norm, edges_init[i]);
}

// ---------------------------------------------------------------------------
extern "C" void kernel_launch(void* const* d_in, const int* in_sizes, int n_in,
                              void* d_out, int out_size, void* d_ws,
                              size_t ws_size, hipStream_t stream) {
  const float* nodes0 = (const float*)d_in[0];
  const float* edges0 = (const float*)d_in[1];
  const int* senders = (const int*)d_in[2];
  const int* receivers = (const int*)d_in[3];
  const float* enc_w1 = (const float*)d_in[4];
  const float* enc_b1 = (const float*)d_in[5];
  const float* enc_w2 = (const float*)d_in[6];
  const float* enc_b2 = (const float*)d_in[7];
  const float* node_w1 = (const float*)d_in[8];
  const float* node_b1 = (const float*)d_in[9];
  const float* node_w2 = (const float*)d_in[10];
  const float* node_b2 = (const float*)d_in[11];
  const float* edge_w1 = (const float*)d_in[12];
  const float* edge_b1 = (const float*)d_in[13];
  const float* edge_w2 = (const float*)d_in[14];
  const float* edge_b2 = (const float*)d_in[15];
  const float* dec_w1 = (const float*)d_in[16];
  const float* dec_b1 = (const float*)d_in[17];
  const float* dec_w2 = (const float*)d_in[18];
  const float* dec_b2 = (const float*)d_in[19];
  const float* alpha = (const float*)d_in[20];

  // Workspace layout (~167.6 MB total):
  char* ws = (char*)d_ws;
  __hip_bfloat16* e = (__hip_bfloat16*)ws;                 // E*16 bf16 = 102.4MB
  float* agg = (float*)(ws + (size_t)N_EDGES * HID * 2);   // N*32 f32 = 12.8MB
  float* nb1 = agg + (size_t)N_NODES * 32;                 // N f32
  float* nb2 = nb1 + N_NODES;                              // N f32
  unsigned int* normbits = (unsigned int*)(nb2 + N_NODES); // 64 B slot
  int* count = (int*)(normbits + 16);                      // N int = 0.4MB
  int* ell = count + N_NODES;                              // N*128 int = 51.2MB

  const int egrid = N_EDGES / BLK;  // 12500 exactly
  const int ngrid = (N_NODES + BLK - 1) / BLK;
  const int ggrid = (N_NODES * 64) / BLK;  // wave per node: 25000 blocks
  const int bgrid = 3520;  // 440 blocks per XCD group x 8 groups (as R4/R5)

  hipMemsetAsync(normbits, 0, sizeof(unsigned int), stream);
  hipMemsetAsync(count, 0, (size_t)N_NODES * sizeof(int), stream);
  k_norm<<<512, BLK, 0, stream>>>(edges0, normbits);
  k_build<<<bgrid, BLK, 0, stream>>>(senders, receivers, count, ell);
  k_encode<<<egrid, BLK, 0, stream>>>(edges0, enc_w1, enc_b1, enc_w2, enc_b2,
                                      normbits, e);
  // round 1
  k_gather<<<ggrid, BLK, 0, stream>>>((const unsigned short*)e, count, ell, agg);
  k_node<<<ngrid, BLK, 0, stream>>>(nodes0, agg, node_w1, node_b1, node_w2,
                                    node_b2, nb1);
  k_edge<<<egrid, BLK, 0, stream>>>(e, senders, receivers, nb1, edge_w1,
                                    edge_b1, edge_w2, edge_b2);
  // round 2
  k_gather<<<ggrid, BLK, 0, stream>>>((const unsigned short*)e, count, ell, agg);
  k_node<<<ngrid, BLK, 0, stream>>>(nb1, agg, node_w1, node_b1, node_w2,
                                    node_b2, nb2);
  k_edge<<<egrid, BLK, 0, stream>>>(e, senders, receivers, nb2, edge_w1,
                                    edge_b1, edge_w2, edge_b2);
  // round 3
  k_gather<<<ggrid, BLK, 0, stream>>>((const unsigned short*)e, count, ell, agg);
  k_node<<<ngrid, BLK, 0, stream>>>(nb2, agg, node_w1, node_b1, node_w2,
                                    node_b2, nb1);
  k_final<<<egrid, BLK, 0, stream>>>(e, senders, receivers, nb1, edge_w1,
                                     edge_b1, edge_w2, edge_b2, dec_w1, dec_b1,
                                     dec_w2, dec_b2, edges0, normbits, alpha,
                                     (float*)d_out);
}